// Round 6
// baseline (154.267 us; speedup 1.0000x reference)
//
#include <hip/hip_runtime.h>
#include <math.h>

#define BB   256   // batch
#define OBS  256
#define HH   1024
#define AA   18
#define NBLK 256   // grid = (64,4)

// clang-native packed f16: + -> v_pk_add_f16, elementwise_max -> v_pk_max_f16
typedef _Float16 h2 __attribute__((ext_vector_type(2)));

static __device__ __forceinline__ h2 u2h(unsigned int u) {
  return __builtin_bit_cast(h2, u);
}
static __device__ __forceinline__ unsigned int h2u(h2 v) {
  return __builtin_bit_cast(unsigned int, v);
}

// Device-scope grid barrier: monotonic counter, target = phase * NBLK.
// __syncthreads + t0 release-fence + atomicAdd; spin; acquire-fence.
// Safe: grid = 256 blocks, LDS 64.3 KB -> 2 blocks/CU capacity, all resident.
static __device__ __forceinline__ void grid_barrier(unsigned int* bar,
                                                    unsigned int target) {
  __syncthreads();
  if (threadIdx.x == 0) {
    __threadfence();  // release: publish this block's global writes
    __hip_atomic_fetch_add(bar, 1u, __ATOMIC_RELAXED, __HIP_MEMORY_SCOPE_AGENT);
    while (__hip_atomic_load(bar, __ATOMIC_RELAXED, __HIP_MEMORY_SCOPE_AGENT) <
           target)
      __builtin_amdgcn_s_sleep(2);
    __threadfence();  // acquire: invalidate stale L1/L2 lines
  }
  __syncthreads();
}

// ---------------------------------------------------------------------------
// mmplus phase (packed f16): out[o][b] = OP_i( W[o][i] + h[i][b] )
// 16 i-splits (64 i each), thread tile 4o x 4b. W f32 -> pk f16 into LDS
// (pitch 514, conflict-free b64 reads). h coalesced dwordx4.
// ---------------------------------------------------------------------------
template <bool IS_MAX>
static __device__ __forceinline__ void mmplus_phase(
    unsigned int* lds, const unsigned int* __restrict__ hpk,
    const float* __restrict__ Wf, unsigned int* __restrict__ opk,
    int og, int bg, int t) {
  constexpr int PITCH = 514;
  const int lane = t & 63;
  const int og2  = lane >> 4;      // o-quad 0..3
  const int bq   = lane & 15;      // b-quad 0..15
  const int s    = __builtin_amdgcn_readfirstlane(t >> 6);  // i-split 0..15

  // ---- stage W tile: 16 rows (one per wave), f32 -> pk f16 in-flight ----
  {
    const int o_l = t >> 6;
    const int c   = t & 63;
    const float4* src = (const float4*)(Wf + (size_t)(og * 16 + o_l) * HH);
    unsigned int* dst = &lds[o_l * PITCH];
#pragma unroll
    for (int k = 0; k < 4; ++k) {
      const float4 v = src[c + 64 * k];
      h2 p0 = {(_Float16)v.x, (_Float16)v.y};
      h2 p1 = {(_Float16)v.z, (_Float16)v.w};
      *(uint2*)&dst[(c + 64 * k) * 2] = make_uint2(h2u(p0), h2u(p1));
    }
  }
  __syncthreads();

  const unsigned int* __restrict__ hp =
      hpk + (size_t)(s * 32) * BB + bg * 64 + bq * 4;
  const _Float16 INIT = (_Float16)(IS_MAX ? -65504.f : 65504.f);
  h2 acc[4][4];
#pragma unroll
  for (int j = 0; j < 4; ++j)
#pragma unroll
    for (int bb = 0; bb < 4; ++bb) acc[j][bb] = (h2){INIT, INIT};

#pragma unroll 4
  for (int it = 0; it < 16; ++it) {
    const int p = it * 2;
    const uint4 h0 = *(const uint4*)(hp + (size_t)p * BB);
    const uint4 h1 = *(const uint4*)(hp + (size_t)(p + 1) * BB);
    const h2 h0v[4] = {u2h(h0.x), u2h(h0.y), u2h(h0.z), u2h(h0.w)};
    const h2 h1v[4] = {u2h(h1.x), u2h(h1.y), u2h(h1.z), u2h(h1.w)};
#pragma unroll
    for (int j = 0; j < 4; ++j) {
      const uint2 wj = *(const uint2*)&lds[(og2 * 4 + j) * PITCH + s * 32 + p];
      const h2 wa = u2h(wj.x);
      const h2 wb = u2h(wj.y);
#pragma unroll
      for (int bb = 0; bb < 4; ++bb) {
        if (IS_MAX) {
          acc[j][bb] = __builtin_elementwise_max(acc[j][bb], wa + h0v[bb]);
          acc[j][bb] = __builtin_elementwise_max(acc[j][bb], wb + h1v[bb]);
        } else {
          acc[j][bb] = __builtin_elementwise_min(acc[j][bb], wa + h0v[bb]);
          acc[j][bb] = __builtin_elementwise_min(acc[j][bb], wb + h1v[bb]);
        }
      }
    }
  }

  // fold even/odd i-partials -> scalar f16 per (o,b), pack o-pairs
  unsigned int opack[2][4];
#pragma unroll
  for (int jp = 0; jp < 2; ++jp)
#pragma unroll
    for (int bb = 0; bb < 4; ++bb) {
      const h2 ae = acc[2 * jp][bb], ao = acc[2 * jp + 1][bb];
      const _Float16 me = IS_MAX ? (ae.x > ae.y ? ae.x : ae.y)
                                 : (ae.x < ae.y ? ae.x : ae.y);
      const _Float16 mo = IS_MAX ? (ao.x > ao.y ? ao.x : ao.y)
                                 : (ao.x < ao.y ? ao.x : ao.y);
      opack[jp][bb] = h2u((h2){me, mo});
    }

  __syncthreads();  // W reads done; reuse lds[] as red[16][8][64]
#pragma unroll
  for (int jp = 0; jp < 2; ++jp) {
    const int op = og2 * 2 + jp;
#pragma unroll
    for (int bb = 0; bb < 4; ++bb)
      lds[s * 512 + op * 64 + bq * 4 + bb] = opack[jp][bb];
  }
  __syncthreads();

  if (t < 512) {
    const int op = t >> 6;
    const int bl = t & 63;
    h2 m = u2h(lds[op * 64 + bl]);
#pragma unroll
    for (int ks = 1; ks < 16; ++ks) {
      const h2 v = u2h(lds[ks * 512 + op * 64 + bl]);
      m = IS_MAX ? __builtin_elementwise_max(m, v)
                 : __builtin_elementwise_min(m, v);
    }
    opk[(size_t)(og * 8 + op) * BB + bg * 64 + bl] = h2u(m);
  }
}

// ---------------------------------------------------------------------------
// Fused pipeline: fc_in -> grid_barrier -> max-plus -> grid_barrier ->
// min-plus -> grid_barrier -> fc_out.  grid (64,4) x 1024 threads.
// Shared: 16448 dwords = 64.3 KB (phase-aliased) -> 2 blocks/CU capacity.
// ---------------------------------------------------------------------------
__global__ __launch_bounds__(1024) void fused_kernel(
    const float* __restrict__ x,    const float* __restrict__ Wi,
    const float* __restrict__ bi,   const float* __restrict__ Wmax,
    const float* __restrict__ Wmin, const float* __restrict__ Wo,
    const float* __restrict__ bo,   unsigned int* __restrict__ h1pk,
    unsigned int* __restrict__ h2pk, unsigned int* __restrict__ h3pk,
    unsigned int* __restrict__ bar, float* __restrict__ q) {
  __shared__ __align__(16) unsigned int S[16448];
  const int t    = threadIdx.x;
  const int lane = t & 63;
  const int wv   = __builtin_amdgcn_readfirstlane(t >> 6);
  const int og   = blockIdx.x;   // 0..63
  const int bg   = blockIdx.y;   // 0..3

  // ================= Phase 1: fc_in =================
  {
    unsigned int* xs = S;                     // [64][129] pk dwords (33 KB)
    float* red = (float*)(S + 64 * 129);      // [8][16][64] f32 (32 KB)
    // stage x slice (rows bg*64..+64) as packed f16, pitch 129 (2-way free)
    {
      const int row = t >> 4;                 // 0..63
      const int c4  = t & 15;                 // 0..15
      const float4* src = (const float4*)(x + (size_t)(bg * 64 + row) * OBS);
#pragma unroll
      for (int k = 0; k < 4; ++k) {
        const float4 v = src[c4 + 16 * k];
        h2 p0 = {(_Float16)v.x, (_Float16)v.y};
        h2 p1 = {(_Float16)v.z, (_Float16)v.w};
        const int col = (c4 + 16 * k) * 2;
        xs[row * 129 + col]     = h2u(p0);
        xs[row * 129 + col + 1] = h2u(p1);
      }
    }
    __syncthreads();

    const int oq = wv & 1;
    const int s  = wv >> 1;        // k-split: 32 k each
    const int o0 = og * 16 + oq * 8;
    const int k0 = s * 32;

    const float* __restrict__ w0 = Wi + (size_t)(o0 + 0) * OBS + k0;
    const float* __restrict__ w1 = Wi + (size_t)(o0 + 1) * OBS + k0;
    const float* __restrict__ w2 = Wi + (size_t)(o0 + 2) * OBS + k0;
    const float* __restrict__ w3 = Wi + (size_t)(o0 + 3) * OBS + k0;
    const float* __restrict__ w4 = Wi + (size_t)(o0 + 4) * OBS + k0;
    const float* __restrict__ w5 = Wi + (size_t)(o0 + 5) * OBS + k0;
    const float* __restrict__ w6 = Wi + (size_t)(o0 + 6) * OBS + k0;
    const float* __restrict__ w7 = Wi + (size_t)(o0 + 7) * OBS + k0;

    float a0 = 0, a1 = 0, a2 = 0, a3 = 0, a4 = 0, a5 = 0, a6 = 0, a7 = 0;
#pragma unroll 8
    for (int kp = 0; kp < 16; ++kp) {
      const h2 xp = u2h(xs[lane * 129 + (k0 >> 1) + kp]);
      const float x0 = (float)xp.x, x1 = (float)xp.y;
      const int k = 2 * kp;
      a0 = fmaf(x0, w0[k], a0); a0 = fmaf(x1, w0[k + 1], a0);
      a1 = fmaf(x0, w1[k], a1); a1 = fmaf(x1, w1[k + 1], a1);
      a2 = fmaf(x0, w2[k], a2); a2 = fmaf(x1, w2[k + 1], a2);
      a3 = fmaf(x0, w3[k], a3); a3 = fmaf(x1, w3[k + 1], a3);
      a4 = fmaf(x0, w4[k], a4); a4 = fmaf(x1, w4[k + 1], a4);
      a5 = fmaf(x0, w5[k], a5); a5 = fmaf(x1, w5[k + 1], a5);
      a6 = fmaf(x0, w6[k], a6); a6 = fmaf(x1, w6[k + 1], a6);
      a7 = fmaf(x0, w7[k], a7); a7 = fmaf(x1, w7[k + 1], a7);
    }

    red[(s * 16 + oq * 8 + 0) * 64 + lane] = a0;
    red[(s * 16 + oq * 8 + 1) * 64 + lane] = a1;
    red[(s * 16 + oq * 8 + 2) * 64 + lane] = a2;
    red[(s * 16 + oq * 8 + 3) * 64 + lane] = a3;
    red[(s * 16 + oq * 8 + 4) * 64 + lane] = a4;
    red[(s * 16 + oq * 8 + 5) * 64 + lane] = a5;
    red[(s * 16 + oq * 8 + 6) * 64 + lane] = a6;
    red[(s * 16 + oq * 8 + 7) * 64 + lane] = a7;
    __syncthreads();

    if (t < 512) {
      const int op = t >> 6;   // o-pair 0..7
      const int bl = t & 63;
      float s0 = 0.f, s1 = 0.f;
#pragma unroll
      for (int ks = 0; ks < 8; ++ks) {
        s0 += red[(ks * 16 + 2 * op) * 64 + bl];
        s1 += red[(ks * 16 + 2 * op + 1) * 64 + bl];
      }
      s0 += bi[og * 16 + 2 * op];
      s1 += bi[og * 16 + 2 * op + 1];
      h2 p = {(_Float16)s0, (_Float16)s1};
      h1pk[(size_t)(og * 8 + op) * BB + bg * 64 + bl] = h2u(p);
    }
  }

  grid_barrier(bar, 1 * NBLK);

  // ================= Phase 2: max-plus =================
  mmplus_phase<true>(S, h1pk, Wmax, h2pk, og, bg, t);

  grid_barrier(bar, 2 * NBLK);

  // ================= Phase 3: min-plus =================
  mmplus_phase<false>(S, h2pk, Wmin, h3pk, og, bg, t);

  grid_barrier(bar, 3 * NBLK);

  // ================= Phase 4: fc_out (blocks og < AA) =================
  if (og < AA) {
    float* red = (float*)S;        // [16][64]
    const int a  = og;
    const int bl = t & 63;
    const int ks = __builtin_amdgcn_readfirstlane(t >> 6);  // 0..15

    const unsigned int* __restrict__ hp =
        h3pk + (size_t)(ks * 32) * BB + bg * 64 + bl;
    const float* __restrict__ w = Wo + (size_t)a * HH + ks * 64;

    float acc = 0.f;
#pragma unroll 8
    for (int d = 0; d < 32; ++d) {
      const h2 hv = u2h(hp[(size_t)d * BB]);
      acc = fmaf((float)hv.x, w[2 * d], acc);
      acc = fmaf((float)hv.y, w[2 * d + 1], acc);
    }
    red[ks * 64 + bl] = acc;
    __syncthreads();

    if (t < 64) {
      float m = bo[a];
#pragma unroll
      for (int ks2 = 0; ks2 < 16; ++ks2) m += red[ks2 * 64 + t];
      q[(size_t)(bg * 64 + t) * AA + a] = m;
    }
  }
}

// ---------------------------------------------------------------------------
extern "C" void kernel_launch(void* const* d_in, const int* in_sizes, int n_in,
                              void* d_out, int out_size, void* d_ws, size_t ws_size,
                              hipStream_t stream) {
  const float* x    = (const float*)d_in[0];
  const float* Wi   = (const float*)d_in[1];
  const float* bi   = (const float*)d_in[2];
  const float* Wmax = (const float*)d_in[3];
  const float* Wmin = (const float*)d_in[4];
  const float* Wo   = (const float*)d_in[5];
  const float* bo   = (const float*)d_in[6];
  float* q = (float*)d_out;

  char* ws = (char*)d_ws;
  unsigned int* h1pk = (unsigned int*)ws;  ws += (size_t)(HH / 2) * BB * 4;  // 512 KB
  unsigned int* h2pk = (unsigned int*)ws;  ws += (size_t)(HH / 2) * BB * 4;
  unsigned int* h3pk = (unsigned int*)ws;  ws += (size_t)(HH / 2) * BB * 4;
  unsigned int* bar  = (unsigned int*)ws;  // barrier counter (zeroed below)

  hipMemsetAsync(bar, 0, 128, stream);
  fused_kernel<<<dim3(HH / 16, BB / 64), 1024, 0, stream>>>(
      x, Wi, bi, Wmax, Wmin, Wo, bo, h1pk, h2pk, h3pk, bar, q);
}

// Round 7
// 114.585 us; speedup vs baseline: 1.3463x; 1.3463x over previous
//
#include <hip/hip_runtime.h>
#include <math.h>

#define BB   256   // batch
#define OBS  256
#define HH   1024
#define AA   18

// clang-native packed f16: + -> v_pk_add_f16, elementwise_max -> v_pk_max_f16
typedef _Float16 h2 __attribute__((ext_vector_type(2)));

static __device__ __forceinline__ h2 u2h(unsigned int u) {
  return __builtin_bit_cast(h2, u);
}
static __device__ __forceinline__ unsigned int h2u(h2 v) {
  return __builtin_bit_cast(unsigned int, v);
}

// ---------------------------------------------------------------------------
// prep: W_max/W_min f32 -> packed f16 dwords [o][i/2] (adjacent i pairs).
// ---------------------------------------------------------------------------
__global__ __launch_bounds__(256) void prep_kernel(
    const float* __restrict__ Wmax, const float* __restrict__ Wmin,
    unsigned int* __restrict__ Wmax16, unsigned int* __restrict__ Wmin16) {
  const int id = blockIdx.x * 256 + threadIdx.x;
  const int NW = (HH * HH) / 4;  // float4 quads per W matrix
  if (id < NW) {
    const float4 v = ((const float4*)Wmax)[id];
    h2 p0 = {(_Float16)v.x, (_Float16)v.y};
    h2 p1 = {(_Float16)v.z, (_Float16)v.w};
    Wmax16[id * 2]     = h2u(p0);
    Wmax16[id * 2 + 1] = h2u(p1);
  } else {
    const int j = id - NW;
    const float4 v = ((const float4*)Wmin)[j];
    h2 p0 = {(_Float16)v.x, (_Float16)v.y};
    h2 p1 = {(_Float16)v.z, (_Float16)v.w};
    Wmin16[j * 2]     = h2u(p0);
    Wmin16[j * 2 + 1] = h2u(p1);
  }
}

// ---------------------------------------------------------------------------
// fc_in: h1pk[o/2][b] = pack_f16( x@W_in^T + b_in ) for o-pair
// grid (H/16, B/64), block 1024 = 8 k-splits x 2 o-octets. lane = b.
// x slice staged via LDS (f32, pitch 257). W_in rows wave-uniform -> s_load.
// ---------------------------------------------------------------------------
__global__ __launch_bounds__(1024) void fc_in_kernel(
    const float* __restrict__ x, const float* __restrict__ Wi,
    const float* __restrict__ bi, unsigned int* __restrict__ h1pk) {
  __shared__ float xs[64][OBS + 1];
  __shared__ float red[8][16][64];
  const int t    = threadIdx.x;
  const int lane = t & 63;
  const int wv   = __builtin_amdgcn_readfirstlane(t >> 6);
  const int oq   = wv & 1;
  const int s    = wv >> 1;        // k-split: 32 k each
  const int og   = blockIdx.x;
  const int bg   = blockIdx.y;
  const int o0   = og * 16 + oq * 8;
  const int k0   = s * 32;

  {
    const int row = t >> 4;          // 0..63
    const int c4  = t & 15;          // 0..15
    const float4* src = (const float4*)(x + (size_t)(bg * 64 + row) * OBS);
#pragma unroll
    for (int k = 0; k < 4; ++k) {
      const float4 v = src[c4 + 16 * k];
      const int col = (c4 + 16 * k) * 4;
      xs[row][col]     = v.x;
      xs[row][col + 1] = v.y;
      xs[row][col + 2] = v.z;
      xs[row][col + 3] = v.w;
    }
  }
  __syncthreads();

  const float* __restrict__ w0 = Wi + (size_t)(o0 + 0) * OBS + k0;
  const float* __restrict__ w1 = Wi + (size_t)(o0 + 1) * OBS + k0;
  const float* __restrict__ w2 = Wi + (size_t)(o0 + 2) * OBS + k0;
  const float* __restrict__ w3 = Wi + (size_t)(o0 + 3) * OBS + k0;
  const float* __restrict__ w4 = Wi + (size_t)(o0 + 4) * OBS + k0;
  const float* __restrict__ w5 = Wi + (size_t)(o0 + 5) * OBS + k0;
  const float* __restrict__ w6 = Wi + (size_t)(o0 + 6) * OBS + k0;
  const float* __restrict__ w7 = Wi + (size_t)(o0 + 7) * OBS + k0;

  float a0 = 0, a1 = 0, a2 = 0, a3 = 0, a4 = 0, a5 = 0, a6 = 0, a7 = 0;
#pragma unroll 8
  for (int k = 0; k < 32; ++k) {
    const float xv = xs[lane][k0 + k];
    a0 = fmaf(xv, w0[k], a0); a1 = fmaf(xv, w1[k], a1);
    a2 = fmaf(xv, w2[k], a2); a3 = fmaf(xv, w3[k], a3);
    a4 = fmaf(xv, w4[k], a4); a5 = fmaf(xv, w5[k], a5);
    a6 = fmaf(xv, w6[k], a6); a7 = fmaf(xv, w7[k], a7);
  }

  red[s][oq * 8 + 0][lane] = a0;  red[s][oq * 8 + 1][lane] = a1;
  red[s][oq * 8 + 2][lane] = a2;  red[s][oq * 8 + 3][lane] = a3;
  red[s][oq * 8 + 4][lane] = a4;  red[s][oq * 8 + 5][lane] = a5;
  red[s][oq * 8 + 6][lane] = a6;  red[s][oq * 8 + 7][lane] = a7;
  __syncthreads();

  if (t < 512) {
    const int op = t >> 6;
    const int bl = t & 63;
    float s0 = 0.f, s1 = 0.f;
#pragma unroll
    for (int ks = 0; ks < 8; ++ks) {
      s0 += red[ks][2 * op][bl];
      s1 += red[ks][2 * op + 1][bl];
    }
    s0 += bi[og * 16 + 2 * op];
    s1 += bi[og * 16 + 2 * op + 1];
    h2 p = {(_Float16)s0, (_Float16)s1};
    h1pk[(size_t)(og * 8 + op) * BB + bg * 64 + bl] = h2u(p);
  }
}

// ---------------------------------------------------------------------------
// mmplus v2 (packed f16): out[o][b] = OP_i( W[o][i] + h[i][b] )
// grid (H/16, B/64), block 1024 = 16 i-splits (64 i each). lane = b.
// Each wave preloads its 64-i h-slice into 32 VGPRs (coalesced b32 loads,
// one waitcnt); W16 pair-dwords are wave-uniform -> scalar s_load, feeding
// v_pk_add_f16 directly from SGPRs. Inner loop: pure VALU, no VMEM/LDS.
// LDS only for the final 16-way i-split reduction.
// ---------------------------------------------------------------------------
template <bool IS_MAX>
__global__ __launch_bounds__(1024) void mmplus_kernel(
    const unsigned int* __restrict__ hpk,   // [H/2][B] dwords (i-pair, b)
    const unsigned int* __restrict__ W16,   // [H][H/2] dwords (o, i-pair)
    unsigned int* __restrict__ opk) {       // [H/2][B]
  __shared__ unsigned int red[16][8][64];   // 32 KB
  const int t    = threadIdx.x;
  const int lane = t & 63;
  const int s    = __builtin_amdgcn_readfirstlane(t >> 6);  // i-split 0..15
  const int og   = blockIdx.x;
  const int bg   = blockIdx.y;
  const int b    = bg * 64 + lane;
  const int p0   = s * 32;                  // first i-pair of this split

  // ---- preload h slice: 32 pair-dwords, each load coalesced over lanes ----
  h2 hreg[32];
  {
    const unsigned int* __restrict__ hp = hpk + (size_t)p0 * BB + b;
#pragma unroll
    for (int p = 0; p < 32; ++p) hreg[p] = u2h(hp[(size_t)p * BB]);
  }

  const unsigned int* __restrict__ wr =
      W16 + (size_t)(og * 16) * (HH / 2) + p0;
  const _Float16 INIT = (_Float16)(IS_MAX ? -65504.f : 65504.f);

  unsigned int res[8];   // 16 o results packed as o-pairs
#pragma unroll 2
  for (int op = 0; op < 8; ++op) {
    h2 accA = (h2){INIT, INIT};
    h2 accB = (h2){INIT, INIT};
    const unsigned int* wa = wr + (size_t)(2 * op) * (HH / 2);
    const unsigned int* wb = wa + (HH / 2);
#pragma unroll
    for (int p = 0; p < 32; ++p) {
      const h2 wva = u2h(wa[p]);     // uniform -> s_load, SGPR operand
      const h2 wvb = u2h(wb[p]);
      if (IS_MAX) {
        accA = __builtin_elementwise_max(accA, wva + hreg[p]);
        accB = __builtin_elementwise_max(accB, wvb + hreg[p]);
      } else {
        accA = __builtin_elementwise_min(accA, wva + hreg[p]);
        accB = __builtin_elementwise_min(accB, wvb + hreg[p]);
      }
    }
    const _Float16 rA = IS_MAX ? (accA.x > accA.y ? accA.x : accA.y)
                               : (accA.x < accA.y ? accA.x : accA.y);
    const _Float16 rB = IS_MAX ? (accB.x > accB.y ? accB.x : accB.y)
                               : (accB.x < accB.y ? accB.x : accB.y);
    res[op] = h2u((h2){rA, rB});
  }

  // ---- 16-way i-split reduction via LDS ----
#pragma unroll
  for (int op = 0; op < 8; ++op) red[s][op][lane] = res[op];
  __syncthreads();

  if (t < 512) {
    const int op = t >> 6;   // 0..7
    const int bl = t & 63;
    h2 m = u2h(red[0][op][bl]);
#pragma unroll
    for (int ks = 1; ks < 16; ++ks) {
      const h2 v = u2h(red[ks][op][bl]);
      m = IS_MAX ? __builtin_elementwise_max(m, v)
                 : __builtin_elementwise_min(m, v);
    }
    opk[(size_t)(og * 8 + op) * BB + bg * 64 + bl] = h2u(m);
  }
}

// ---------------------------------------------------------------------------
// fc_out: q[b][a] = bo[a] + dot(h3[:,b], W_out[a,:])
// grid (A, B/64), block 1024 = 16 k-splits x 64 b.
// ---------------------------------------------------------------------------
__global__ __launch_bounds__(1024) void fc_out_kernel(
    const unsigned int* __restrict__ h3pk, const float* __restrict__ Wo,
    const float* __restrict__ bo, float* __restrict__ q) {
  __shared__ float red[16][64];
  const int a  = blockIdx.x;
  const int bg = blockIdx.y;
  const int t  = threadIdx.x;
  const int bl = t & 63;
  const int ks = __builtin_amdgcn_readfirstlane(t >> 6);  // 0..15

  const unsigned int* __restrict__ hp =
      h3pk + (size_t)(ks * 32) * BB + bg * 64 + bl;
  const float* __restrict__ w = Wo + (size_t)a * HH + ks * 64;

  float acc = 0.f;
#pragma unroll 8
  for (int d = 0; d < 32; ++d) {
    const h2 hv = u2h(hp[(size_t)d * BB]);
    acc = fmaf((float)hv.x, w[2 * d], acc);
    acc = fmaf((float)hv.y, w[2 * d + 1], acc);
  }
  red[ks][bl] = acc;
  __syncthreads();

  if (t < 64) {
    float m = bo[a];
#pragma unroll
    for (int ks2 = 0; ks2 < 16; ++ks2) m += red[ks2][t];
    q[(size_t)(bg * 64 + t) * AA + a] = m;
  }
}

// ---------------------------------------------------------------------------
extern "C" void kernel_launch(void* const* d_in, const int* in_sizes, int n_in,
                              void* d_out, int out_size, void* d_ws, size_t ws_size,
                              hipStream_t stream) {
  const float* x    = (const float*)d_in[0];
  const float* Wi   = (const float*)d_in[1];
  const float* bi   = (const float*)d_in[2];
  const float* Wmax = (const float*)d_in[3];
  const float* Wmin = (const float*)d_in[4];
  const float* Wo   = (const float*)d_in[5];
  const float* bo   = (const float*)d_in[6];
  float* q = (float*)d_out;

  char* ws = (char*)d_ws;
  unsigned int* Wmax16 = (unsigned int*)ws;  ws += (size_t)HH * (HH / 2) * 4;  // 2 MB
  unsigned int* Wmin16 = (unsigned int*)ws;  ws += (size_t)HH * (HH / 2) * 4;  // 2 MB
  unsigned int* h1pk   = (unsigned int*)ws;  ws += (size_t)(HH / 2) * BB * 4;  // 512 KB
  unsigned int* h2pk   = (unsigned int*)ws;  ws += (size_t)(HH / 2) * BB * 4;
  unsigned int* h3pk   = (unsigned int*)ws;

  prep_kernel<<<2 * (HH * HH / 4) / 256, 256, 0, stream>>>(
      Wmax, Wmin, Wmax16, Wmin16);
  fc_in_kernel<<<dim3(HH / 16, BB / 64), 1024, 0, stream>>>(x, Wi, bi, h1pk);
  mmplus_kernel<true ><<<dim3(HH / 16, BB / 64), 1024, 0, stream>>>(h1pk, Wmax16, h2pk);
  mmplus_kernel<false><<<dim3(HH / 16, BB / 64), 1024, 0, stream>>>(h2pk, Wmin16, h3pk);
  fc_out_kernel<<<dim3(AA, BB / 64), 1024, 0, stream>>>(h3pk, Wo, bo, q);
}

// Round 8
// 106.636 us; speedup vs baseline: 1.4467x; 1.0745x over previous
//
#include <hip/hip_runtime.h>
#include <math.h>

#define BB   256   // batch
#define OBS  256
#define HH   1024
#define AA   18

// clang-native packed f16: + -> v_pk_add_f16, elementwise_max -> v_pk_max_f16
typedef _Float16 h2 __attribute__((ext_vector_type(2)));

static __device__ __forceinline__ h2 u2h(unsigned int u) {
  return __builtin_bit_cast(h2, u);
}
static __device__ __forceinline__ unsigned int h2u(h2 v) {
  return __builtin_bit_cast(unsigned int, v);
}

// ---------------------------------------------------------------------------
// fc_in: h1pk[o/2][b] = pack_f16( x@W_in^T + b_in ) for o-pair
// grid (H/16, B/64), block 1024 = 8 k-splits x 2 o-octets. lane = b.
// x slice staged via LDS (f32, pitch 257). W_in rows wave-uniform -> s_load.
// (R5 structure, unchanged — proven best so far.)
// ---------------------------------------------------------------------------
__global__ __launch_bounds__(1024) void fc_in_kernel(
    const float* __restrict__ x, const float* __restrict__ Wi,
    const float* __restrict__ bi, unsigned int* __restrict__ h1pk) {
  __shared__ float xs[64][OBS + 1];
  __shared__ float red[8][16][64];
  const int t    = threadIdx.x;
  const int lane = t & 63;
  const int wv   = __builtin_amdgcn_readfirstlane(t >> 6);
  const int oq   = wv & 1;
  const int s    = wv >> 1;        // k-split: 32 k each
  const int og   = blockIdx.x;
  const int bg   = blockIdx.y;
  const int o0   = og * 16 + oq * 8;
  const int k0   = s * 32;

  {
    const int row = t >> 4;          // 0..63
    const int c4  = t & 15;          // 0..15
    const float4* src = (const float4*)(x + (size_t)(bg * 64 + row) * OBS);
#pragma unroll
    for (int k = 0; k < 4; ++k) {
      const float4 v = src[c4 + 16 * k];
      const int col = (c4 + 16 * k) * 4;
      xs[row][col]     = v.x;
      xs[row][col + 1] = v.y;
      xs[row][col + 2] = v.z;
      xs[row][col + 3] = v.w;
    }
  }
  __syncthreads();

  const float* __restrict__ w0 = Wi + (size_t)(o0 + 0) * OBS + k0;
  const float* __restrict__ w1 = Wi + (size_t)(o0 + 1) * OBS + k0;
  const float* __restrict__ w2 = Wi + (size_t)(o0 + 2) * OBS + k0;
  const float* __restrict__ w3 = Wi + (size_t)(o0 + 3) * OBS + k0;
  const float* __restrict__ w4 = Wi + (size_t)(o0 + 4) * OBS + k0;
  const float* __restrict__ w5 = Wi + (size_t)(o0 + 5) * OBS + k0;
  const float* __restrict__ w6 = Wi + (size_t)(o0 + 6) * OBS + k0;
  const float* __restrict__ w7 = Wi + (size_t)(o0 + 7) * OBS + k0;

  float a0 = 0, a1 = 0, a2 = 0, a3 = 0, a4 = 0, a5 = 0, a6 = 0, a7 = 0;
#pragma unroll 8
  for (int k = 0; k < 32; ++k) {
    const float xv = xs[lane][k0 + k];
    a0 = fmaf(xv, w0[k], a0); a1 = fmaf(xv, w1[k], a1);
    a2 = fmaf(xv, w2[k], a2); a3 = fmaf(xv, w3[k], a3);
    a4 = fmaf(xv, w4[k], a4); a5 = fmaf(xv, w5[k], a5);
    a6 = fmaf(xv, w6[k], a6); a7 = fmaf(xv, w7[k], a7);
  }

  red[s][oq * 8 + 0][lane] = a0;  red[s][oq * 8 + 1][lane] = a1;
  red[s][oq * 8 + 2][lane] = a2;  red[s][oq * 8 + 3][lane] = a3;
  red[s][oq * 8 + 4][lane] = a4;  red[s][oq * 8 + 5][lane] = a5;
  red[s][oq * 8 + 6][lane] = a6;  red[s][oq * 8 + 7][lane] = a7;
  __syncthreads();

  if (t < 512) {
    const int op = t >> 6;
    const int bl = t & 63;
    float s0 = 0.f, s1 = 0.f;
#pragma unroll
    for (int ks = 0; ks < 8; ++ks) {
      s0 += red[ks][2 * op][bl];
      s1 += red[ks][2 * op + 1][bl];
    }
    s0 += bi[og * 16 + 2 * op];
    s1 += bi[og * 16 + 2 * op + 1];
    h2 p = {(_Float16)s0, (_Float16)s1};
    h1pk[(size_t)(og * 8 + op) * BB + bg * 64 + bl] = h2u(p);
  }
}

// ---------------------------------------------------------------------------
// mmplus v3 (packed f16): out[o][b] = OP_i( W[o][i] + h[i][b] )
// grid (H/8, B/64) = 512 blocks, block 1024 = 16 i-splits (64 i each).
// o-tile halved vs v1 (8 o/block): LDS 16.4 KB -> 2 blocks/CU co-resident
// = 8 waves/SIMD (v1 was 4). W f32 -> pk f16 into LDS in-flight (pitch 514,
// conflict-free b64 reads). Thread tile 2o x 4b. h coalesced dwordx4.
// W-sharing blocks are 128 apart in linear id (128%8==0 -> same XCD).
// ---------------------------------------------------------------------------
template <bool IS_MAX>
__global__ __launch_bounds__(1024) void mmplus_kernel(
    const unsigned int* __restrict__ hpk,   // [H/2][B] dwords (i-pair, b)
    const float* __restrict__ Wf,           // [H][H] f32 (o, i)
    unsigned int* __restrict__ opk) {       // [H/2][B]
  constexpr int PITCH = 514;
  __shared__ __align__(16) unsigned int lds[8 * PITCH];  // 16.4 KB; red aliases
  const int t    = threadIdx.x;
  const int lane = t & 63;
  const int og2  = lane >> 4;      // o-pair group 0..3
  const int bq   = lane & 15;      // b-quad 0..15
  const int s    = __builtin_amdgcn_readfirstlane(t >> 6);  // i-split 0..15
  const int og   = blockIdx.x;     // 0..127, 8 o each
  const int bg   = blockIdx.y;

  // ---- stage W tile: 8 rows (two waves per row), f32 -> pk f16 ----
  {
    const int o_l = t >> 7;        // 0..7
    const int c   = t & 127;
    const float4* src = (const float4*)(Wf + (size_t)(og * 8 + o_l) * HH);
    unsigned int* dst = &lds[o_l * PITCH];
#pragma unroll
    for (int k = 0; k < 2; ++k) {
      const float4 v = src[c + 128 * k];
      h2 p0 = {(_Float16)v.x, (_Float16)v.y};
      h2 p1 = {(_Float16)v.z, (_Float16)v.w};
      *(uint2*)&dst[(c + 128 * k) * 2] = make_uint2(h2u(p0), h2u(p1));
    }
  }
  __syncthreads();

  const unsigned int* __restrict__ hp =
      hpk + (size_t)(s * 32) * BB + bg * 64 + bq * 4;
  const _Float16 INIT = (_Float16)(IS_MAX ? -65504.f : 65504.f);
  h2 acc[2][4];
#pragma unroll
  for (int j = 0; j < 2; ++j)
#pragma unroll
    for (int bb = 0; bb < 4; ++bb) acc[j][bb] = (h2){INIT, INIT};

  // 32 i-pairs for this split, 2 pairs (4 i) per iteration
#pragma unroll 4
  for (int it = 0; it < 16; ++it) {
    const int p = it * 2;
    const uint4 h0 = *(const uint4*)(hp + (size_t)p * BB);
    const uint4 h1 = *(const uint4*)(hp + (size_t)(p + 1) * BB);
    const h2 h0v[4] = {u2h(h0.x), u2h(h0.y), u2h(h0.z), u2h(h0.w)};
    const h2 h1v[4] = {u2h(h1.x), u2h(h1.y), u2h(h1.z), u2h(h1.w)};
#pragma unroll
    for (int j = 0; j < 2; ++j) {
      const uint2 wj = *(const uint2*)&lds[(og2 * 2 + j) * PITCH + s * 32 + p];
      const h2 wa = u2h(wj.x);
      const h2 wb = u2h(wj.y);
#pragma unroll
      for (int bb = 0; bb < 4; ++bb) {
        if (IS_MAX) {
          acc[j][bb] = __builtin_elementwise_max(acc[j][bb], wa + h0v[bb]);
          acc[j][bb] = __builtin_elementwise_max(acc[j][bb], wb + h1v[bb]);
        } else {
          acc[j][bb] = __builtin_elementwise_min(acc[j][bb], wa + h0v[bb]);
          acc[j][bb] = __builtin_elementwise_min(acc[j][bb], wb + h1v[bb]);
        }
      }
    }
  }

  // fold even/odd i-partials -> scalar f16 per (o,b); pack this thread's
  // o-pair (j=0 even row, j=1 odd row)
  unsigned int opack[4];
#pragma unroll
  for (int bb = 0; bb < 4; ++bb) {
    const h2 ae = acc[0][bb], ao = acc[1][bb];
    const _Float16 me = IS_MAX ? (ae.x > ae.y ? ae.x : ae.y)
                               : (ae.x < ae.y ? ae.x : ae.y);
    const _Float16 mo = IS_MAX ? (ao.x > ao.y ? ao.x : ao.y)
                               : (ao.x < ao.y ? ao.x : ao.y);
    opack[bb] = h2u((h2){me, mo});
  }

  __syncthreads();  // W reads done; reuse lds[] as red[16][4][64] (16 KB)
#pragma unroll
  for (int bb = 0; bb < 4; ++bb)
    lds[s * 256 + og2 * 64 + bq * 4 + bb] = opack[bb];
  __syncthreads();

  if (t < 256) {
    const int op = t >> 6;   // o-pair 0..3
    const int bl = t & 63;
    h2 m = u2h(lds[op * 64 + bl]);
#pragma unroll
    for (int ks = 1; ks < 16; ++ks) {
      const h2 v = u2h(lds[ks * 256 + op * 64 + bl]);
      m = IS_MAX ? __builtin_elementwise_max(m, v)
                 : __builtin_elementwise_min(m, v);
    }
    opk[(size_t)(og * 4 + op) * BB + bg * 64 + bl] = h2u(m);
  }
}

// ---------------------------------------------------------------------------
// fc_out: q[b][a] = bo[a] + dot(h3[:,b], W_out[a,:])
// grid (A, B/64), block 1024 = 16 k-splits x 64 b. (R5, unchanged.)
// ---------------------------------------------------------------------------
__global__ __launch_bounds__(1024) void fc_out_kernel(
    const unsigned int* __restrict__ h3pk, const float* __restrict__ Wo,
    const float* __restrict__ bo, float* __restrict__ q) {
  __shared__ float red[16][64];
  const int a  = blockIdx.x;
  const int bg = blockIdx.y;
  const int t  = threadIdx.x;
  const int bl = t & 63;
  const int ks = __builtin_amdgcn_readfirstlane(t >> 6);  // 0..15

  const unsigned int* __restrict__ hp =
      h3pk + (size_t)(ks * 32) * BB + bg * 64 + bl;
  const float* __restrict__ w = Wo + (size_t)a * HH + ks * 64;

  float acc = 0.f;
#pragma unroll 8
  for (int d = 0; d < 32; ++d) {
    const h2 hv = u2h(hp[(size_t)d * BB]);
    acc = fmaf((float)hv.x, w[2 * d], acc);
    acc = fmaf((float)hv.y, w[2 * d + 1], acc);
  }
  red[ks][bl] = acc;
  __syncthreads();

  if (t < 64) {
    float m = bo[a];
#pragma unroll
    for (int ks2 = 0; ks2 < 16; ++ks2) m += red[ks2][t];
    q[(size_t)(bg * 64 + t) * AA + a] = m;
  }
}

// ---------------------------------------------------------------------------
extern "C" void kernel_launch(void* const* d_in, const int* in_sizes, int n_in,
                              void* d_out, int out_size, void* d_ws, size_t ws_size,
                              hipStream_t stream) {
  const float* x    = (const float*)d_in[0];
  const float* Wi   = (const float*)d_in[1];
  const float* bi   = (const float*)d_in[2];
  const float* Wmax = (const float*)d_in[3];
  const float* Wmin = (const float*)d_in[4];
  const float* Wo   = (const float*)d_in[5];
  const float* bo   = (const float*)d_in[6];
  float* q = (float*)d_out;

  char* ws = (char*)d_ws;
  unsigned int* h1pk = (unsigned int*)ws;  ws += (size_t)(HH / 2) * BB * 4;  // 512 KB
  unsigned int* h2pk = (unsigned int*)ws;  ws += (size_t)(HH / 2) * BB * 4;
  unsigned int* h3pk = (unsigned int*)ws;

  fc_in_kernel<<<dim3(HH / 16, BB / 64), 1024, 0, stream>>>(x, Wi, bi, h1pk);
  mmplus_kernel<true ><<<dim3(HH / 8, BB / 64), 1024, 0, stream>>>(h1pk, Wmax, h2pk);
  mmplus_kernel<false><<<dim3(HH / 8, BB / 64), 1024, 0, stream>>>(h2pk, Wmin, h3pk);
  fc_out_kernel<<<dim3(AA, BB / 64), 1024, 0, stream>>>(h3pk, Wo, bo, q);
}